// Round 7
// baseline (153.143 us; speedup 1.0000x reference)
//
#include <hip/hip_runtime.h>

#define N_SAMP 16384
#define D_FEAT 64
#define TILE 128
#define NTILE 128                 // 128 tile-rows
#define SPLIT 8                   // wave-segments per row-pair
#define NPAIR (NTILE / 2)         // 64
#define NBLOCKS (NPAIR * SPLIT)   // 512 blocks = exactly 2/CU
#define TPP (NTILE + 1)           // 129 tiles per pair (constant)
#define SEG_BASE (TPP / SPLIT)    // 16
#define SEG_REM (TPP % SPLIT)     // 1

typedef __attribute__((ext_vector_type(8))) short bf16x8;
typedef __attribute__((ext_vector_type(4))) float f32x4;
typedef __attribute__((ext_vector_type(2))) float f32x2;
typedef __attribute__((ext_vector_type(4))) unsigned short u16x4;

__device__ __forceinline__ unsigned short f2bf_rne(float f) {
  union { float f; unsigned u; } v;
  v.f = f;
  unsigned u = v.u;
  return (unsigned short)((u + 0x7FFFu + ((u >> 16) & 1u)) >> 16);
}

// Prepass: xb[i][k] = bf16(y_i * x[i][k]); blocks 0..63 also reduce
// {relu(alpha), relu(xi), y} into per-block triples via plain stores.
__global__ __launch_bounds__(256) void prep_kernel(
    const float* __restrict__ x, const float* __restrict__ y,
    const float* __restrict__ alpha, const float* __restrict__ xi,
    unsigned short* __restrict__ xb, float4* __restrict__ psums) {
  int t = blockIdx.x * 256 + threadIdx.x;  // 0 .. 262143
  int base = t * 4;
  int row = base >> 6;  // D=64
  float yv = y[row];
  float4 v = *(const float4*)(x + base);
  u16x4 o;
  o.x = f2bf_rne(v.x * yv);
  o.y = f2bf_rne(v.y * yv);
  o.z = f2bf_rne(v.z * yv);
  o.w = f2bf_rne(v.w * yv);
  *(u16x4*)(xb + base) = o;

  if (blockIdx.x < (N_SAMP / 256)) {
    float a = fmaxf(alpha[t], 0.0f);
    float xr = fmaxf(xi[t], 0.0f);
    float yy = y[t];
#pragma unroll
    for (int off = 32; off > 0; off >>= 1) {
      a += __shfl_down(a, off, 64);
      xr += __shfl_down(xr, off, 64);
      yy += __shfl_down(yy, off, 64);
    }
    __shared__ float ra[4], rx[4], ry[4];
    int wv = threadIdx.x >> 6;
    if ((threadIdx.x & 63) == 0) {
      ra[wv] = a;
      rx[wv] = xr;
      ry[wv] = yy;
    }
    __syncthreads();
    if (threadIdx.x == 0)
      psums[blockIdx.x] =
          make_float4(ra[0] + ra[1] + ra[2] + ra[3],
                      rx[0] + rx[1] + rx[2] + rx[3],
                      ry[0] + ry[1] + ry[2] + ry[3], 0.0f);
  }
}

// R7: DEPTH-2 register double-buffer. R6 proved the stall is invariant to
// the B data path (LDS vs direct-L2 both ~6500cy/tile/SIMD, 60% idle at
// 2 waves/SIMD). Remaining theory: exposed VMEM latency/queueing — the
// in-flight window was only the epilogue (~840cy issue). Now tile n+1's
// loads (ycol FIRST, bfr after -> counted vmcnt lets init start while bfr
// in flight) are issued at the top of iteration n into the *other* named
// register set (A/B, 2x-unrolled loop, all static indexing), consumed one
// full iteration later. s_setprio(1) wraps the MFMA cluster (waves here
// are desynchronized -> scheduler has roles to arbitrate).
// Geometry unchanged: 512 blocks, 4 waves x 64x64 quadrants, no LDS.
__global__ __launch_bounds__(256, 2) void tile_kernel(
    const unsigned short* __restrict__ xb,
    const float* __restrict__ alpha,
    const float* __restrict__ y,
    const int* __restrict__ coeffp,
    const int* __restrict__ degp,
    float* __restrict__ partials) {
  __shared__ float wred[4];

  const int tid = threadIdx.x;
  const int lane = tid & 63;
  const int wv = tid >> 6;  // wave 0..3
  const int wm = wv >> 1;   // quadrant row (0..1)
  const int wn = wv & 1;    // quadrant col (0..1)
  const int lr = lane & 15;
  const int q = lane >> 4;  // quad 0..3

  // ---- balanced schedule: pair p = {rows p, 127-p}, segment sb ----
  const int p = blockIdx.x >> 3;
  const int sb = blockIdx.x & (SPLIT - 1);
  const int i1 = p, i2 = NTILE - 1 - p;
  const int cnt1 = NTILE - p;  // tiles in row i1 (j = p..127)
  const int g0 = sb * SEG_BASE + (sb < SEG_REM ? sb : SEG_REM);
  const int gcnt = SEG_BASE + (sb < SEG_REM ? 1 : 0);

  auto g_to_ij = [&](int g, int& i, int& j) {
    if (g < cnt1) {
      i = i1;
      j = p + g;
    } else {
      i = i2;
      j = i2 + (g - cnt1);
    }
  };

  const char* xbytes = (const char*)xb;
  const float fco = (float)coeffp[0];
  const int deg = degp[0];

  f32x2 yr[4][2], ar[4][2];
  auto load_rows = [&](int ic) {
#pragma unroll
    for (int mt = 0; mt < 4; ++mt) {
      int idx = ic * TILE + wm * 64 + mt * 16 + q * 4;
      float4 yv = *(const float4*)(y + idx);
      float4 av = *(const float4*)(alpha + idx);
      yr[mt][0] = (f32x2){yv.x, yv.y};
      yr[mt][1] = (f32x2){yv.z, yv.w};
      ar[mt][0] = (f32x2){fmaxf(av.x, 0.0f), fmaxf(av.y, 0.0f)};
      ar[mt][1] = (f32x2){fmaxf(av.z, 0.0f), fmaxf(av.w, 0.0f)};
    }
  };

  bf16x8 af[4][2];
  auto read_af_g = [&](int rowtile) {
    const char* base = xbytes + (((size_t)(rowtile * TILE + wm * 64)) << 7);
#pragma unroll
    for (int mt = 0; mt < 4; ++mt) {
      int r = mt * 16 + lr;
#pragma unroll
      for (int kc = 0; kc < 2; ++kc)
        af[mt][kc] = *(const bf16x8*)(base + (r << 7) + ((kc * 4 + q) << 4));
    }
  };

  f32x2 rsum[4][2];
#pragma unroll
  for (int mt = 0; mt < 4; ++mt)
    for (int h = 0; h < 2; ++h) rsum[mt][h] = (f32x2){0.0f, 0.0f};
  float lane_total = 0.0f;

  auto flush_rsum = [&]() {
#pragma unroll
    for (int mt = 0; mt < 4; ++mt) {
      f32x2 s = rsum[mt][0] * ar[mt][0] + rsum[mt][1] * ar[mt][1];
      lane_total += s.x + s.y;
      rsum[mt][0] = (f32x2){0.0f, 0.0f};
      rsum[mt][1] = (f32x2){0.0f, 0.0f};
    }
  };

  // ---- deferred-epilogue state (tile n-1) ----
  f32x4 acc[4][4];
  float ycolP[4], wcolP[4];
  bool diagP = false;
  bool have_prev = false;

  auto epilogue_prev = [&]() {
    if (deg == 3) {
      if (diagP) {
#pragma unroll
        for (int nt = 0; nt < 4; ++nt) {
          f32x2 cs = {0.0f, 0.0f};
#pragma unroll
          for (int mt = 0; mt < 4; ++mt) {
#pragma unroll
            for (int h = 0; h < 2; ++h) {
              f32x2 T = {acc[mt][nt][2 * h], acc[mt][nt][2 * h + 1]};
              f32x2 T2 = T * T;
              cs += T2 * T;
            }
          }
          lane_total = fmaf(cs.x + cs.y, wcolP[nt], lane_total);
        }
      } else {
#pragma unroll
        for (int nt = 0; nt < 4; ++nt) {
          f32x2 cs = {0.0f, 0.0f};
#pragma unroll
          for (int mt = 0; mt < 4; ++mt) {
#pragma unroll
            for (int h = 0; h < 2; ++h) {
              f32x2 T = {acc[mt][nt][2 * h], acc[mt][nt][2 * h + 1]};
              f32x2 T2 = T * T;
              f32x2 P = T2 * T;
              cs += P;
              rsum[mt][h] += P;  // a_i applied at flush (fixed per row)
            }
          }
          lane_total = fmaf(cs.x + cs.y, wcolP[nt], lane_total);
        }
      }
    } else {
      // generic-degree fallback (even degree restores y_i y_j sign);
      // runs BEFORE any row-switch load_rows of the current iteration.
#pragma unroll
      for (int nt = 0; nt < 4; ++nt) {
        float cs = 0.0f;
#pragma unroll
        for (int mt = 0; mt < 4; ++mt) {
          float ys[4] = {yr[mt][0].x, yr[mt][0].y, yr[mt][1].x, yr[mt][1].y};
          float as[4] = {ar[mt][0].x, ar[mt][0].y, ar[mt][1].x, ar[mt][1].y};
#pragma unroll
          for (int rg = 0; rg < 4; ++rg) {
            float T = acc[mt][nt][rg];
            float pw = 1.0f;
            for (int d = 0; d < deg; ++d) pw *= T;
            if (!(deg & 1)) pw *= ys[rg] * ycolP[nt];
            cs += pw;
            if (!diagP) lane_total += pw * as[rg];
          }
        }
        lane_total = fmaf(cs, wcolP[nt], lane_total);
      }
    }
  };

// ---- depth-2 load/compute/rotate macros (all static indexing) ----
#define ISSUE_LOADS(JN, YC, WR, BF)                                      \
  {                                                                      \
    _Pragma("unroll") for (int nt = 0; nt < 4; ++nt) {                   \
      int jj = (JN)*TILE + wn * 64 + nt * 16 + lr;                       \
      YC[nt] = y[jj];                                                    \
      WR[nt] = alpha[jj];                                                \
    }                                                                    \
    const char* bb = xbytes + (((size_t)((JN)*TILE + wn * 64)) << 7);    \
    _Pragma("unroll") for (int nt = 0; nt < 4; ++nt) {                   \
      int rr = nt * 16 + lr;                                             \
      _Pragma("unroll") for (int kc = 0; kc < 2; ++kc)                   \
          BF[nt][kc] =                                                   \
              *(const bf16x8*)(bb + (rr << 7) + ((kc * 4 + q) << 4));    \
    }                                                                    \
  }

#define INIT_MFMA(YC, BF)                                                \
  {                                                                      \
    float ysc[4];                                                        \
    _Pragma("unroll") for (int nt = 0; nt < 4; ++nt) ysc[nt] =           \
        YC[nt] * fco;                                                    \
    _Pragma("unroll") for (int mt = 0; mt < 4; ++mt)                     \
        _Pragma("unroll") for (int nt = 0; nt < 4; ++nt) {               \
      f32x2 lo = yr[mt][0] * ysc[nt];                                    \
      f32x2 hi = yr[mt][1] * ysc[nt];                                    \
      acc[mt][nt][0] = lo.x;                                             \
      acc[mt][nt][1] = lo.y;                                             \
      acc[mt][nt][2] = hi.x;                                             \
      acc[mt][nt][3] = hi.y;                                             \
    }                                                                    \
    __builtin_amdgcn_s_setprio(1);                                       \
    _Pragma("unroll") for (int kc = 0; kc < 2; ++kc)                     \
        _Pragma("unroll") for (int mt = 0; mt < 4; ++mt)                 \
            _Pragma("unroll") for (int nt = 0; nt < 4; ++nt)             \
                acc[mt][nt] = __builtin_amdgcn_mfma_f32_16x16x32_bf16(   \
                    af[mt][kc], BF[nt][kc], acc[mt][nt], 0, 0, 0);       \
    __builtin_amdgcn_s_setprio(0);                                       \
  }

#define ROTATE(YC, WR, DIAG)                                             \
  {                                                                      \
    _Pragma("unroll") for (int nt = 0; nt < 4; ++nt) {                   \
      ycolP[nt] = YC[nt];                                                \
      wcolP[nt] = fmaxf(WR[nt], 0.0f);                                   \
    }                                                                    \
    diagP = (DIAG);                                                      \
  }

  // ---- named double-buffer register sets ----
  float ycA[4], wrA[4], ycB[4], wrB[4];
  bf16x8 bfA[4][2], bfB[4][2];

  // ---- prologue: tile g0's loads into set A; first row's A/y/alpha ----
  int icur, jfirst;
  g_to_ij(g0, icur, jfirst);
  ISSUE_LOADS(jfirst, ycA, wrA, bfA);
  load_rows(icur);
  read_af_g(icur);

  for (int it = 0; it < gcnt; it += 2) {
    // ======== even half: current tile in set A ========
    {
      int g = g0 + it;
      int i, j;
      g_to_ij(g, i, j);
      if (it + 1 < gcnt) {
        int in_, jn;
        g_to_ij(g + 1, in_, jn);
        ISSUE_LOADS(jn, ycB, wrB, bfB);  // next tile, full-iteration window
      }
      if (have_prev) epilogue_prev();
      if (i != icur) {
        flush_rsum();
        load_rows(i);
        read_af_g(i);
        icur = i;
      }
      INIT_MFMA(ycA, bfA);
      ROTATE(ycA, wrA, j == i);
      have_prev = true;
    }
    // ======== odd half: current tile in set B ========
    if (it + 1 < gcnt) {
      int g = g0 + it + 1;
      int i, j;
      g_to_ij(g, i, j);
      if (it + 2 < gcnt) {
        int in_, jn;
        g_to_ij(g + 1, in_, jn);
        ISSUE_LOADS(jn, ycA, wrA, bfA);
      }
      epilogue_prev();
      if (i != icur) {
        flush_rsum();
        load_rows(i);
        read_af_g(i);
        icur = i;
      }
      INIT_MFMA(ycB, bfB);
      ROTATE(ycB, wrB, j == i);
    }
  }

  // ---- drain: last tile's epilogue + last row's flush ----
  epilogue_prev();
  flush_rsum();

  // ---- the only block sync: final 4-wave reduce ----
#pragma unroll
  for (int off = 32; off > 0; off >>= 1)
    lane_total += __shfl_down(lane_total, off, 64);
  if (lane == 0) wred[wv] = lane_total;
  __syncthreads();
  if (tid == 0)
    partials[blockIdx.x] = wred[0] + wred[1] + wred[2] + wred[3];
}

__global__ __launch_bounds__(256) void finalize_kernel(
    const float* __restrict__ partials,
    const float4* __restrict__ psums,
    const float* __restrict__ bp,
    const int* __restrict__ Cp,
    const int* __restrict__ lamp,
    float* __restrict__ out) {
  double tsum = 0.0, sa = 0.0, sx = 0.0, sy = 0.0;
  for (int i = threadIdx.x; i < NBLOCKS; i += 256) tsum += (double)partials[i];
  if (threadIdx.x < (N_SAMP / 256)) {  // 64 triples, wave 0 only
    float4 v = psums[threadIdx.x];
    sa = (double)v.x;
    sx = (double)v.y;
    sy = (double)v.z;
  }
#pragma unroll
  for (int off = 32; off > 0; off >>= 1) {
    tsum += __shfl_down(tsum, off, 64);
    sa += __shfl_down(sa, off, 64);
    sx += __shfl_down(sx, off, 64);
    sy += __shfl_down(sy, off, 64);
  }
  __shared__ double red[4][4];
  int wv = threadIdx.x >> 6;
  if ((threadIdx.x & 63) == 0) {
    red[wv][0] = tsum;
    red[wv][1] = sa;
    red[wv][2] = sx;
    red[wv][3] = sy;
  }
  __syncthreads();
  if (threadIdx.x == 0) {
    double T = red[0][0] + red[1][0] + red[2][0] + red[3][0];
    double A = red[0][1] + red[1][1] + red[2][1] + red[3][1];
    double X = red[0][2] + red[1][2] + red[2][2] + red[3][2];
    double Y = red[0][3] + red[1][3] + red[2][3] + red[3][3];
    double b = (double)bp[0];
    double Cc = (double)Cp[0];
    double lam = (double)lamp[0];
    double mean = (T + b * Y - (double)N_SAMP + X) / (double)N_SAMP;
    out[0] = (float)(0.5 * A + Cc * X + lam * mean);
  }
}

extern "C" void kernel_launch(void* const* d_in, const int* in_sizes, int n_in,
                              void* d_out, int out_size, void* d_ws,
                              size_t ws_size, hipStream_t stream) {
  const float* x = (const float*)d_in[0];
  const float* y = (const float*)d_in[1];
  const float* alpha = (const float*)d_in[2];
  const float* xi = (const float*)d_in[3];
  const float* b = (const float*)d_in[4];
  const int* coeff = (const int*)d_in[5];
  const int* degree = (const int*)d_in[6];
  const int* C = (const int*)d_in[7];
  const int* lambd = (const int*)d_in[8];

  unsigned short* xb = (unsigned short*)d_ws;  // 2 MB
  char* pbase = (char*)d_ws + (size_t)N_SAMP * D_FEAT * 2;
  float* partials = (float*)pbase;  // 512 floats
  float4* psums = (float4*)(pbase + ((NBLOCKS * 4 + 255) & ~255));  // 64 f4

  prep_kernel<<<(N_SAMP * D_FEAT) / (4 * 256), 256, 0, stream>>>(x, y, alpha,
                                                                 xi, xb, psums);

  tile_kernel<<<NBLOCKS, 256, 0, stream>>>(xb, alpha, y, coeff, degree,
                                           partials);

  finalize_kernel<<<1, 256, 0, stream>>>(partials, psums, b, C, lambd,
                                         (float*)d_out);
}

// Round 8
// 130.171 us; speedup vs baseline: 1.1765x; 1.1765x over previous
//
#include <hip/hip_runtime.h>

#define N_SAMP 16384
#define D_FEAT 64
#define TILE 128
#define NTILE 128                 // 128 row-tiles (128 rows each)
#define NCHUNK 256                // 256 col-chunks (64 cols each)
#define SPLIT 12                  // blocks per row-pair
#define NPAIR (NTILE / 2)         // 64
#define NBLOCKS (NPAIR * SPLIT)   // 768 blocks = exactly 3/CU
#define TPP 258                   // col-chunks per pair: (256-2p)+(2p+2)
#define SEG_BASE (TPP / SPLIT)    // 21
#define SEG_REM (TPP % SPLIT)     // 6

typedef __attribute__((ext_vector_type(8))) short bf16x8;
typedef __attribute__((ext_vector_type(4))) float f32x4;
typedef __attribute__((ext_vector_type(2))) float f32x2;
typedef __attribute__((ext_vector_type(4))) unsigned short u16x4;

__device__ __forceinline__ unsigned short f2bf_rne(float f) {
  union { float f; unsigned u; } v;
  v.f = f;
  unsigned u = v.u;
  return (unsigned short)((u + 0x7FFFu + ((u >> 16) & 1u)) >> 16);
}

// Prepass: xb[i][k] = bf16(y_i * x[i][k]); blocks 0..63 also reduce
// {relu(alpha), relu(xi), y} into per-block triples via plain stores.
__global__ __launch_bounds__(256) void prep_kernel(
    const float* __restrict__ x, const float* __restrict__ y,
    const float* __restrict__ alpha, const float* __restrict__ xi,
    unsigned short* __restrict__ xb, float4* __restrict__ psums) {
  int t = blockIdx.x * 256 + threadIdx.x;  // 0 .. 262143
  int base = t * 4;
  int row = base >> 6;  // D=64
  float yv = y[row];
  float4 v = *(const float4*)(x + base);
  u16x4 o;
  o.x = f2bf_rne(v.x * yv);
  o.y = f2bf_rne(v.y * yv);
  o.z = f2bf_rne(v.z * yv);
  o.w = f2bf_rne(v.w * yv);
  *(u16x4*)(xb + base) = o;

  if (blockIdx.x < (N_SAMP / 256)) {
    float a = fmaxf(alpha[t], 0.0f);
    float xr = fmaxf(xi[t], 0.0f);
    float yy = y[t];
#pragma unroll
    for (int off = 32; off > 0; off >>= 1) {
      a += __shfl_down(a, off, 64);
      xr += __shfl_down(xr, off, 64);
      yy += __shfl_down(yy, off, 64);
    }
    __shared__ float ra[4], rx[4], ry[4];
    int wv = threadIdx.x >> 6;
    if ((threadIdx.x & 63) == 0) {
      ra[wv] = a;
      rx[wv] = xr;
      ry[wv] = yy;
    }
    __syncthreads();
    if (threadIdx.x == 0)
      psums[blockIdx.x] =
          make_float4(ra[0] + ra[1] + ra[2] + ra[3],
                      rx[0] + rx[1] + rx[2] + rx[3],
                      ry[0] + ry[1] + ry[2] + ry[3], 0.0f);
  }
}

// R8: TLP test designed to the register budget. launch_bounds(256,3) ->
// 170 regs/wave cap; per-wave state shrunk to ~150 by halving the quadrant
// to 64x32 (acc[4][2]=32 AGPR, bfr[2][2]=16, af 32, rows 40, cols 8).
// 768 blocks (pair p rows {p,127-p}, 258 64-col chunks, SPLIT=12) = exactly
// 3 blocks/CU = 3 waves/SIMD (1.5x R6's TLP). Structure = R6's proven
// no-LDS deferred-epilogue loop (B direct from L2 — R6 showed the B path
// is irrelevant). Stagger dropped (R3: neutral). VALIDITY GATE: WRITE_SIZE
// must stay <= ~6MB; a ballooned WRITE_SIZE means spill -> invalid.
__global__ __launch_bounds__(256, 3) void tile_kernel(
    const unsigned short* __restrict__ xb,
    const float* __restrict__ alpha,
    const float* __restrict__ y,
    const int* __restrict__ coeffp,
    const int* __restrict__ degp,
    float* __restrict__ partials) {
  __shared__ float wred[4];

  const int tid = threadIdx.x;
  const int lane = tid & 63;
  const int wv = tid >> 6;  // wave 0..3
  const int wm = wv >> 1;   // row half (0..1): rows wm*64..+64
  const int wn = wv & 1;    // col half (0..1): cols wn*32..+32 of the chunk
  const int lr = lane & 15;
  const int q = lane >> 4;  // quad 0..3

  // ---- schedule: pair p = rows {p, 127-p}; 64-wide col-chunks ----
  const int p = blockIdx.x / SPLIT;       // pair 0..63
  const int sb = blockIdx.x % SPLIT;
  const int i1 = p, i2 = NTILE - 1 - p;
  const int c1 = NCHUNK - 2 * p;          // chunks in row i1 (j64 = 2p..255)
  const int g0 = sb * SEG_BASE + (sb < SEG_REM ? sb : SEG_REM);
  const int gcnt = SEG_BASE + (sb < SEG_REM ? 1 : 0);

  auto g_to_ij = [&](int g, int& i, int& j) {
    if (g < c1) {
      i = i1;
      j = 2 * p + g;              // j64 within row i1
    } else {
      i = i2;
      j = 2 * i2 + (g - c1);      // j64 within row i2 (starts at 2*i2)
    }
  };

  const char* xbytes = (const char*)xb;
  const float fco = (float)coeffp[0];
  const int deg = degp[0];

  f32x2 yr[4][2], ar[4][2];
  auto load_rows = [&](int ic) {
#pragma unroll
    for (int mt = 0; mt < 4; ++mt) {
      int idx = ic * TILE + wm * 64 + mt * 16 + q * 4;
      float4 yv = *(const float4*)(y + idx);
      float4 av = *(const float4*)(alpha + idx);
      yr[mt][0] = (f32x2){yv.x, yv.y};
      yr[mt][1] = (f32x2){yv.z, yv.w};
      ar[mt][0] = (f32x2){fmaxf(av.x, 0.0f), fmaxf(av.y, 0.0f)};
      ar[mt][1] = (f32x2){fmaxf(av.z, 0.0f), fmaxf(av.w, 0.0f)};
    }
  };

  bf16x8 af[4][2];
  auto read_af_g = [&](int rowtile) {
    const char* base = xbytes + (((size_t)(rowtile * TILE + wm * 64)) << 7);
#pragma unroll
    for (int mt = 0; mt < 4; ++mt) {
      int r = mt * 16 + lr;
#pragma unroll
      for (int kc = 0; kc < 2; ++kc)
        af[mt][kc] = *(const bf16x8*)(base + (r << 7) + ((kc * 4 + q) << 4));
    }
  };

  f32x2 rsum[4][2];
#pragma unroll
  for (int mt = 0; mt < 4; ++mt)
    for (int h = 0; h < 2; ++h) rsum[mt][h] = (f32x2){0.0f, 0.0f};
  float lane_total = 0.0f;

  auto flush_rsum = [&]() {
#pragma unroll
    for (int mt = 0; mt < 4; ++mt) {
      f32x2 s = rsum[mt][0] * ar[mt][0] + rsum[mt][1] * ar[mt][1];
      lane_total += s.x + s.y;
      rsum[mt][0] = (f32x2){0.0f, 0.0f};
      rsum[mt][1] = (f32x2){0.0f, 0.0f};
    }
  };

  // ---- deferred-epilogue state (tile n-1) ----
  f32x4 acc[4][2];
  float ycolP[2], wcolP[2];
  bool diagP = false;
  bool have_prev = false;

  auto epilogue_prev = [&]() {
    if (deg == 3) {
      if (diagP) {
#pragma unroll
        for (int nt = 0; nt < 2; ++nt) {
          f32x2 cs = {0.0f, 0.0f};
#pragma unroll
          for (int mt = 0; mt < 4; ++mt) {
#pragma unroll
            for (int h = 0; h < 2; ++h) {
              f32x2 T = {acc[mt][nt][2 * h], acc[mt][nt][2 * h + 1]};
              f32x2 T2 = T * T;
              cs += T2 * T;
            }
          }
          lane_total = fmaf(cs.x + cs.y, wcolP[nt], lane_total);
        }
      } else {
#pragma unroll
        for (int nt = 0; nt < 2; ++nt) {
          f32x2 cs = {0.0f, 0.0f};
#pragma unroll
          for (int mt = 0; mt < 4; ++mt) {
#pragma unroll
            for (int h = 0; h < 2; ++h) {
              f32x2 T = {acc[mt][nt][2 * h], acc[mt][nt][2 * h + 1]};
              f32x2 T2 = T * T;
              f32x2 P = T2 * T;
              cs += P;
              rsum[mt][h] += P;  // a_i applied at flush (fixed per row)
            }
          }
          lane_total = fmaf(cs.x + cs.y, wcolP[nt], lane_total);
        }
      }
    } else {
      // generic-degree fallback (even degree restores y_i y_j sign);
      // runs BEFORE any row-switch load_rows of the current iteration.
#pragma unroll
      for (int nt = 0; nt < 2; ++nt) {
        float cs = 0.0f;
#pragma unroll
        for (int mt = 0; mt < 4; ++mt) {
          float ys[4] = {yr[mt][0].x, yr[mt][0].y, yr[mt][1].x, yr[mt][1].y};
          float as[4] = {ar[mt][0].x, ar[mt][0].y, ar[mt][1].x, ar[mt][1].y};
#pragma unroll
          for (int rg = 0; rg < 4; ++rg) {
            float T = acc[mt][nt][rg];
            float pw = 1.0f;
            for (int d = 0; d < deg; ++d) pw *= T;
            if (!(deg & 1)) pw *= ys[rg] * ycolP[nt];
            cs += pw;
            if (!diagP) lane_total += pw * as[rg];
          }
        }
        lane_total = fmaf(cs, wcolP[nt], lane_total);
      }
    }
  };

  // ---- prologue: first row's A/y/alpha ----
  int icur;
  {
    int j0;
    g_to_ij(g0, icur, j0);
    load_rows(icur);
    read_af_g(icur);
  }

  for (int it = 0; it < gcnt; ++it) {
    int g = g0 + it;
    int i, j;
    g_to_ij(g, i, j);

    // ---- 1. issue this tile's B fragments (direct from global, L2-hot) ----
    const char* bbase = xbytes + (((size_t)(j * 64 + wn * 32)) << 7);
    bf16x8 bfr[2][2];
#pragma unroll
    for (int nt = 0; nt < 2; ++nt) {
      int rr = nt * 16 + lr;
#pragma unroll
      for (int kc = 0; kc < 2; ++kc)
        bfr[nt][kc] = *(const bf16x8*)(bbase + (rr << 7) + ((kc * 4 + q) << 4));
    }

    // ---- 2. issue this tile's column y/alpha ----
    float ycolN[2], wrawN[2];
#pragma unroll
    for (int nt = 0; nt < 2; ++nt) {
      int jj = j * 64 + wn * 32 + nt * 16 + lr;
      ycolN[nt] = y[jj];
      wrawN[nt] = alpha[jj];
    }

    // ---- 3. previous tile's epilogue runs in the load shadow ----
    if (have_prev) epilogue_prev();

    // ---- 4. row switch (after epilogue: flush uses old row's ar) ----
    if (i != icur) {
      flush_rsum();
      load_rows(i);
      read_af_g(i);  // global, L2-hot; once per block typically
      icur = i;
    }

    // ---- 5. acc init (y_i * y_j * coeff) + MFMA ----
    float ysc[2];
#pragma unroll
    for (int nt = 0; nt < 2; ++nt) ysc[nt] = ycolN[nt] * fco;

#pragma unroll
    for (int mt = 0; mt < 4; ++mt) {
#pragma unroll
      for (int nt = 0; nt < 2; ++nt) {
        f32x2 lo = yr[mt][0] * ysc[nt];
        f32x2 hi = yr[mt][1] * ysc[nt];
        acc[mt][nt][0] = lo.x;
        acc[mt][nt][1] = lo.y;
        acc[mt][nt][2] = hi.x;
        acc[mt][nt][3] = hi.y;
      }
    }

#pragma unroll
    for (int kc = 0; kc < 2; ++kc) {
#pragma unroll
      for (int mt = 0; mt < 4; ++mt) {
#pragma unroll
        for (int nt = 0; nt < 2; ++nt) {
          acc[mt][nt] = __builtin_amdgcn_mfma_f32_16x16x32_bf16(
              af[mt][kc], bfr[nt][kc], acc[mt][nt], 0, 0, 0);
        }
      }
    }

    // ---- 6. rotate deferred state ----
#pragma unroll
    for (int nt = 0; nt < 2; ++nt) {
      ycolP[nt] = ycolN[nt];
      wcolP[nt] = fmaxf(wrawN[nt], 0.0f);
    }
    diagP = ((j >> 1) == i);  // 64-chunk inside the diagonal 128-tile
    have_prev = true;
  }

  // ---- drain: last tile's epilogue + last row's flush ----
  epilogue_prev();
  flush_rsum();

  // ---- the only block sync: final 4-wave reduce ----
#pragma unroll
  for (int off = 32; off > 0; off >>= 1)
    lane_total += __shfl_down(lane_total, off, 64);
  if (lane == 0) wred[wv] = lane_total;
  __syncthreads();
  if (tid == 0)
    partials[blockIdx.x] = wred[0] + wred[1] + wred[2] + wred[3];
}

__global__ __launch_bounds__(256) void finalize_kernel(
    const float* __restrict__ partials,
    const float4* __restrict__ psums,
    const float* __restrict__ bp,
    const int* __restrict__ Cp,
    const int* __restrict__ lamp,
    float* __restrict__ out) {
  double tsum = 0.0, sa = 0.0, sx = 0.0, sy = 0.0;
  for (int i = threadIdx.x; i < NBLOCKS; i += 256) tsum += (double)partials[i];
  if (threadIdx.x < (N_SAMP / 256)) {  // 64 triples, wave 0 only
    float4 v = psums[threadIdx.x];
    sa = (double)v.x;
    sx = (double)v.y;
    sy = (double)v.z;
  }
#pragma unroll
  for (int off = 32; off > 0; off >>= 1) {
    tsum += __shfl_down(tsum, off, 64);
    sa += __shfl_down(sa, off, 64);
    sx += __shfl_down(sx, off, 64);
    sy += __shfl_down(sy, off, 64);
  }
  __shared__ double red[4][4];
  int wv = threadIdx.x >> 6;
  if ((threadIdx.x & 63) == 0) {
    red[wv][0] = tsum;
    red[wv][1] = sa;
    red[wv][2] = sx;
    red[wv][3] = sy;
  }
  __syncthreads();
  if (threadIdx.x == 0) {
    double T = red[0][0] + red[1][0] + red[2][0] + red[3][0];
    double A = red[0][1] + red[1][1] + red[2][1] + red[3][1];
    double X = red[0][2] + red[1][2] + red[2][2] + red[3][2];
    double Y = red[0][3] + red[1][3] + red[2][3] + red[3][3];
    double b = (double)bp[0];
    double Cc = (double)Cp[0];
    double lam = (double)lamp[0];
    double mean = (T + b * Y - (double)N_SAMP + X) / (double)N_SAMP;
    out[0] = (float)(0.5 * A + Cc * X + lam * mean);
  }
}

extern "C" void kernel_launch(void* const* d_in, const int* in_sizes, int n_in,
                              void* d_out, int out_size, void* d_ws,
                              size_t ws_size, hipStream_t stream) {
  const float* x = (const float*)d_in[0];
  const float* y = (const float*)d_in[1];
  const float* alpha = (const float*)d_in[2];
  const float* xi = (const float*)d_in[3];
  const float* b = (const float*)d_in[4];
  const int* coeff = (const int*)d_in[5];
  const int* degree = (const int*)d_in[6];
  const int* C = (const int*)d_in[7];
  const int* lambd = (const int*)d_in[8];

  unsigned short* xb = (unsigned short*)d_ws;  // 2 MB
  char* pbase = (char*)d_ws + (size_t)N_SAMP * D_FEAT * 2;
  float* partials = (float*)pbase;  // 768 floats
  float4* psums = (float4*)(pbase + ((NBLOCKS * 4 + 255) & ~255));  // 64 f4

  prep_kernel<<<(N_SAMP * D_FEAT) / (4 * 256), 256, 0, stream>>>(x, y, alpha,
                                                                 xi, xb, psums);

  tile_kernel<<<NBLOCKS, 256, 0, stream>>>(xb, alpha, y, coeff, degree,
                                           partials);

  finalize_kernel<<<1, 256, 0, stream>>>(partials, psums, b, C, lambd,
                                         (float*)d_out);
}

// Round 9
// 114.921 us; speedup vs baseline: 1.3326x; 1.1327x over previous
//
#include <hip/hip_runtime.h>

#define N_SAMP 16384
#define D_FEAT 64
#define TILE 128
#define NTILE 128                 // 128 tile-rows
#define SPLIT 8                   // wave-segments per row-pair
#define NPAIR (NTILE / 2)         // 64
#define NBLOCKS (NPAIR * SPLIT)   // 512 blocks = exactly 2/CU
#define TPP (NTILE + 1)           // 129 tiles per pair (constant)
#define SEG_BASE (TPP / SPLIT)    // 16
#define SEG_REM (TPP % SPLIT)     // 1

typedef __attribute__((ext_vector_type(8))) short bf16x8;
typedef __attribute__((ext_vector_type(4))) float f32x4;
typedef __attribute__((ext_vector_type(2))) float f32x2;
typedef __attribute__((ext_vector_type(4))) unsigned short u16x4;

__device__ __forceinline__ unsigned short f2bf_rne(float f) {
  union { float f; unsigned u; } v;
  v.f = f;
  unsigned u = v.u;
  return (unsigned short)((u + 0x7FFFu + ((u >> 16) & 1u)) >> 16);
}

// Prepass: xb[i][k] = bf16(y_i * x[i][k]); blocks 0..63 additionally
// (a) write the packed per-sample column record yw[i] = {y_i, relu(a_i)}
//     (halves the tile kernel's per-tile column VMEM instructions), and
// (b) reduce {relu(alpha), relu(xi), y} into per-block triples.
__global__ __launch_bounds__(256) void prep_kernel(
    const float* __restrict__ x, const float* __restrict__ y,
    const float* __restrict__ alpha, const float* __restrict__ xi,
    unsigned short* __restrict__ xb, float2* __restrict__ yw,
    float4* __restrict__ psums) {
  int t = blockIdx.x * 256 + threadIdx.x;  // 0 .. 262143
  int base = t * 4;
  int row = base >> 6;  // D=64
  float yv = y[row];
  float4 v = *(const float4*)(x + base);
  u16x4 o;
  o.x = f2bf_rne(v.x * yv);
  o.y = f2bf_rne(v.y * yv);
  o.z = f2bf_rne(v.z * yv);
  o.w = f2bf_rne(v.w * yv);
  *(u16x4*)(xb + base) = o;

  if (blockIdx.x < (N_SAMP / 256)) {
    float a = fmaxf(alpha[t], 0.0f);
    float xr = fmaxf(xi[t], 0.0f);
    float yy = y[t];
    yw[t] = make_float2(yy, a);  // packed column record
#pragma unroll
    for (int off = 32; off > 0; off >>= 1) {
      a += __shfl_down(a, off, 64);
      xr += __shfl_down(xr, off, 64);
      yy += __shfl_down(yy, off, 64);
    }
    __shared__ float ra[4], rx[4], ry[4];
    int wv = threadIdx.x >> 6;
    if ((threadIdx.x & 63) == 0) {
      ra[wv] = a;
      rx[wv] = xr;
      ry[wv] = yy;
    }
    __syncthreads();
    if (threadIdx.x == 0)
      psums[blockIdx.x] =
          make_float4(ra[0] + ra[1] + ra[2] + ra[3],
                      rx[0] + rx[1] + rx[2] + rx[3],
                      ry[0] + ry[1] + ry[2] + ry[3], 0.0f);
  }
}

// R9: VMEM-instruction-count probe on the proven R6 structure (no-LDS,
// deferred-epilogue, 43.1us). R8 exonerated TLP (3 waves/SIMD ~= 2); R2/R3
// exonerated pipeline depth; R6 exonerated the B data path. Remaining
// counter-consistent suspect: per-CU TA/L1 address throughput (~16cy per
// 64-lane VMEM instr; 8 waves x 16 instr/tile ~= 63% busy). This round
// cuts instrs/wave-tile 16 -> 12: columns load ONE packed yw (dwordx2)
// instead of separate y + alpha, fmax moved to prep. s_setprio(1) wraps
// the MFMA cluster. Everything else byte-identical to R6.
__global__ __launch_bounds__(256, 2) void tile_kernel(
    const unsigned short* __restrict__ xb,
    const float* __restrict__ alpha,
    const float* __restrict__ y,
    const float2* __restrict__ yw,
    const int* __restrict__ coeffp,
    const int* __restrict__ degp,
    float* __restrict__ partials) {
  __shared__ float wred[4];

  const int tid = threadIdx.x;
  const int lane = tid & 63;
  const int wv = tid >> 6;  // wave 0..3
  const int wm = wv >> 1;   // quadrant row (0..1)
  const int wn = wv & 1;    // quadrant col (0..1)
  const int lr = lane & 15;
  const int q = lane >> 4;  // quad 0..3

  // ---- balanced schedule: pair p = {rows p, 127-p}, segment sb ----
  const int p = blockIdx.x >> 3;
  const int sb = blockIdx.x & (SPLIT - 1);
  const int i1 = p, i2 = NTILE - 1 - p;
  const int cnt1 = NTILE - p;  // tiles in row i1 (j = p..127)
  const int g0 = sb * SEG_BASE + (sb < SEG_REM ? sb : SEG_REM);
  const int gcnt = SEG_BASE + (sb < SEG_REM ? 1 : 0);

  auto g_to_ij = [&](int g, int& i, int& j) {
    if (g < cnt1) {
      i = i1;
      j = p + g;
    } else {
      i = i2;
      j = i2 + (g - cnt1);
    }
  };

  const char* xbytes = (const char*)xb;
  const float fco = (float)coeffp[0];
  const int deg = degp[0];

  f32x2 yr[4][2], ar[4][2];
  auto load_rows = [&](int ic) {
#pragma unroll
    for (int mt = 0; mt < 4; ++mt) {
      int idx = ic * TILE + wm * 64 + mt * 16 + q * 4;
      float4 yv = *(const float4*)(y + idx);
      float4 av = *(const float4*)(alpha + idx);
      yr[mt][0] = (f32x2){yv.x, yv.y};
      yr[mt][1] = (f32x2){yv.z, yv.w};
      ar[mt][0] = (f32x2){fmaxf(av.x, 0.0f), fmaxf(av.y, 0.0f)};
      ar[mt][1] = (f32x2){fmaxf(av.z, 0.0f), fmaxf(av.w, 0.0f)};
    }
  };

  bf16x8 af[4][2];
  auto read_af_g = [&](int rowtile) {
    const char* base = xbytes + (((size_t)(rowtile * TILE + wm * 64)) << 7);
#pragma unroll
    for (int mt = 0; mt < 4; ++mt) {
      int r = mt * 16 + lr;
#pragma unroll
      for (int kc = 0; kc < 2; ++kc)
        af[mt][kc] = *(const bf16x8*)(base + (r << 7) + ((kc * 4 + q) << 4));
    }
  };

  f32x2 rsum[4][2];
#pragma unroll
  for (int mt = 0; mt < 4; ++mt)
    for (int h = 0; h < 2; ++h) rsum[mt][h] = (f32x2){0.0f, 0.0f};
  float lane_total = 0.0f;

  auto flush_rsum = [&]() {
#pragma unroll
    for (int mt = 0; mt < 4; ++mt) {
      f32x2 s = rsum[mt][0] * ar[mt][0] + rsum[mt][1] * ar[mt][1];
      lane_total += s.x + s.y;
      rsum[mt][0] = (f32x2){0.0f, 0.0f};
      rsum[mt][1] = (f32x2){0.0f, 0.0f};
    }
  };

  // ---- deferred-epilogue state (tile n-1) ----
  f32x4 acc[4][4];
  float ycolP[4], wcolP[4];
  bool diagP = false;
  bool have_prev = false;

  auto epilogue_prev = [&]() {
    if (deg == 3) {
      if (diagP) {
#pragma unroll
        for (int nt = 0; nt < 4; ++nt) {
          f32x2 cs = {0.0f, 0.0f};
#pragma unroll
          for (int mt = 0; mt < 4; ++mt) {
#pragma unroll
            for (int h = 0; h < 2; ++h) {
              f32x2 T = {acc[mt][nt][2 * h], acc[mt][nt][2 * h + 1]};
              f32x2 T2 = T * T;
              cs += T2 * T;
            }
          }
          lane_total = fmaf(cs.x + cs.y, wcolP[nt], lane_total);
        }
      } else {
#pragma unroll
        for (int nt = 0; nt < 4; ++nt) {
          f32x2 cs = {0.0f, 0.0f};
#pragma unroll
          for (int mt = 0; mt < 4; ++mt) {
#pragma unroll
            for (int h = 0; h < 2; ++h) {
              f32x2 T = {acc[mt][nt][2 * h], acc[mt][nt][2 * h + 1]};
              f32x2 T2 = T * T;
              f32x2 P = T2 * T;
              cs += P;
              rsum[mt][h] += P;  // a_i applied at flush (fixed per row)
            }
          }
          lane_total = fmaf(cs.x + cs.y, wcolP[nt], lane_total);
        }
      }
    } else {
      // generic-degree fallback (even degree restores y_i y_j sign);
      // runs BEFORE any row-switch load_rows of the current iteration.
#pragma unroll
      for (int nt = 0; nt < 4; ++nt) {
        float cs = 0.0f;
#pragma unroll
        for (int mt = 0; mt < 4; ++mt) {
          float ys[4] = {yr[mt][0].x, yr[mt][0].y, yr[mt][1].x, yr[mt][1].y};
          float as[4] = {ar[mt][0].x, ar[mt][0].y, ar[mt][1].x, ar[mt][1].y};
#pragma unroll
          for (int rg = 0; rg < 4; ++rg) {
            float T = acc[mt][nt][rg];
            float pw = 1.0f;
            for (int d = 0; d < deg; ++d) pw *= T;
            if (!(deg & 1)) pw *= ys[rg] * ycolP[nt];
            cs += pw;
            if (!diagP) lane_total += pw * as[rg];
          }
        }
        lane_total = fmaf(cs, wcolP[nt], lane_total);
      }
    }
  };

  // ---- prologue: first row's A/y/alpha ----
  int icur;
  {
    int j0;
    g_to_ij(g0, icur, j0);
    load_rows(icur);
    read_af_g(icur);
  }

  for (int it = 0; it < gcnt; ++it) {
    int g = g0 + it;
    int i, j;
    g_to_ij(g, i, j);

    // ---- 1. issue this tile's B fragments (direct from global, L2-hot) ----
    const char* bbase = xbytes + (((size_t)(j * TILE + wn * 64)) << 7);
    bf16x8 bfr[4][2];
#pragma unroll
    for (int nt = 0; nt < 4; ++nt) {
      int rr = nt * 16 + lr;
#pragma unroll
      for (int kc = 0; kc < 2; ++kc)
        bfr[nt][kc] = *(const bf16x8*)(bbase + (rr << 7) + ((kc * 4 + q) << 4));
    }

    // ---- 2. issue this tile's packed column records (4 dwordx2, was 8) ----
    const float2* cwp = yw + j * TILE + wn * 64 + lr;
    float2 cw0 = cwp[0];
    float2 cw1 = cwp[16];
    float2 cw2 = cwp[32];
    float2 cw3 = cwp[48];

    // ---- 3. previous tile's epilogue runs in the load shadow ----
    if (have_prev) epilogue_prev();

    // ---- 4. row switch (after epilogue: flush uses old row's ar) ----
    if (i != icur) {
      flush_rsum();
      load_rows(i);
      read_af_g(i);  // global, L2-hot; rare (once per block typically)
      icur = i;
    }

    // ---- 5. acc init (y_i * y_j * coeff) + MFMA ----
    float ycolN[4] = {cw0.x, cw1.x, cw2.x, cw3.x};
    float wcolN[4] = {cw0.y, cw1.y, cw2.y, cw3.y};
    float ysc[4];
#pragma unroll
    for (int nt = 0; nt < 4; ++nt) ysc[nt] = ycolN[nt] * fco;

#pragma unroll
    for (int mt = 0; mt < 4; ++mt) {
#pragma unroll
      for (int nt = 0; nt < 4; ++nt) {
        f32x2 lo = yr[mt][0] * ysc[nt];
        f32x2 hi = yr[mt][1] * ysc[nt];
        acc[mt][nt][0] = lo.x;
        acc[mt][nt][1] = lo.y;
        acc[mt][nt][2] = hi.x;
        acc[mt][nt][3] = hi.y;
      }
    }

    __builtin_amdgcn_s_setprio(1);
#pragma unroll
    for (int kc = 0; kc < 2; ++kc) {
#pragma unroll
      for (int mt = 0; mt < 4; ++mt) {
#pragma unroll
        for (int nt = 0; nt < 4; ++nt) {
          acc[mt][nt] = __builtin_amdgcn_mfma_f32_16x16x32_bf16(
              af[mt][kc], bfr[nt][kc], acc[mt][nt], 0, 0, 0);
        }
      }
    }
    __builtin_amdgcn_s_setprio(0);

    // ---- 6. rotate deferred state (wcol already relu'd by prep) ----
#pragma unroll
    for (int nt = 0; nt < 4; ++nt) {
      ycolP[nt] = ycolN[nt];
      wcolP[nt] = wcolN[nt];
    }
    diagP = (j == i);
    have_prev = true;
  }

  // ---- drain: last tile's epilogue + last row's flush ----
  epilogue_prev();
  flush_rsum();

  // ---- the only block sync: final 4-wave reduce ----
#pragma unroll
  for (int off = 32; off > 0; off >>= 1)
    lane_total += __shfl_down(lane_total, off, 64);
  if (lane == 0) wred[wv] = lane_total;
  __syncthreads();
  if (tid == 0)
    partials[blockIdx.x] = wred[0] + wred[1] + wred[2] + wred[3];
}

__global__ __launch_bounds__(256) void finalize_kernel(
    const float* __restrict__ partials,
    const float4* __restrict__ psums,
    const float* __restrict__ bp,
    const int* __restrict__ Cp,
    const int* __restrict__ lamp,
    float* __restrict__ out) {
  double tsum = 0.0, sa = 0.0, sx = 0.0, sy = 0.0;
  for (int i = threadIdx.x; i < NBLOCKS; i += 256) tsum += (double)partials[i];
  if (threadIdx.x < (N_SAMP / 256)) {  // 64 triples, wave 0 only
    float4 v = psums[threadIdx.x];
    sa = (double)v.x;
    sx = (double)v.y;
    sy = (double)v.z;
  }
#pragma unroll
  for (int off = 32; off > 0; off >>= 1) {
    tsum += __shfl_down(tsum, off, 64);
    sa += __shfl_down(sa, off, 64);
    sx += __shfl_down(sx, off, 64);
    sy += __shfl_down(sy, off, 64);
  }
  __shared__ double red[4][4];
  int wv = threadIdx.x >> 6;
  if ((threadIdx.x & 63) == 0) {
    red[wv][0] = tsum;
    red[wv][1] = sa;
    red[wv][2] = sx;
    red[wv][3] = sy;
  }
  __syncthreads();
  if (threadIdx.x == 0) {
    double T = red[0][0] + red[1][0] + red[2][0] + red[3][0];
    double A = red[0][1] + red[1][1] + red[2][1] + red[3][1];
    double X = red[0][2] + red[1][2] + red[2][2] + red[3][2];
    double Y = red[0][3] + red[1][3] + red[2][3] + red[3][3];
    double b = (double)bp[0];
    double Cc = (double)Cp[0];
    double lam = (double)lamp[0];
    double mean = (T + b * Y - (double)N_SAMP + X) / (double)N_SAMP;
    out[0] = (float)(0.5 * A + Cc * X + lam * mean);
  }
}

extern "C" void kernel_launch(void* const* d_in, const int* in_sizes, int n_in,
                              void* d_out, int out_size, void* d_ws,
                              size_t ws_size, hipStream_t stream) {
  const float* x = (const float*)d_in[0];
  const float* y = (const float*)d_in[1];
  const float* alpha = (const float*)d_in[2];
  const float* xi = (const float*)d_in[3];
  const float* b = (const float*)d_in[4];
  const int* coeff = (const int*)d_in[5];
  const int* degree = (const int*)d_in[6];
  const int* C = (const int*)d_in[7];
  const int* lambd = (const int*)d_in[8];

  unsigned short* xb = (unsigned short*)d_ws;                  // 2 MB
  char* base2 = (char*)d_ws + (size_t)N_SAMP * D_FEAT * 2;     // +2 MB
  float2* yw = (float2*)base2;                                 // 128 KB
  char* pbase = base2 + (size_t)N_SAMP * sizeof(float2);
  float* partials = (float*)pbase;  // 512 floats
  float4* psums = (float4*)(pbase + ((NBLOCKS * 4 + 255) & ~255));  // 64 f4

  prep_kernel<<<(N_SAMP * D_FEAT) / (4 * 256), 256, 0, stream>>>(
      x, y, alpha, xi, xb, yw, psums);

  tile_kernel<<<NBLOCKS, 256, 0, stream>>>(xb, alpha, y, yw, coeff, degree,
                                           partials);

  finalize_kernel<<<1, 256, 0, stream>>>(partials, psums, b, C, lambd,
                                         (float*)d_out);
}

// Round 10
// 113.197 us; speedup vs baseline: 1.3529x; 1.0152x over previous
//
#include <hip/hip_runtime.h>

#define N_SAMP 16384
#define D_FEAT 64
#define TILE 128
#define NTILE 128                 // 128 tile-rows
#define SPLIT 4                   // wave-segments per row-pair (R10: was 8)
#define NPAIR (NTILE / 2)         // 64
#define NBLOCKS (NPAIR * SPLIT)   // 256 blocks = exactly 1/CU
#define TPP (NTILE + 1)           // 129 tiles per pair (constant)
#define SEG_BASE (TPP / SPLIT)    // 32
#define SEG_REM (TPP % SPLIT)     // 1

typedef __attribute__((ext_vector_type(8))) short bf16x8;
typedef __attribute__((ext_vector_type(4))) float f32x4;
typedef __attribute__((ext_vector_type(2))) float f32x2;
typedef __attribute__((ext_vector_type(4))) unsigned short u16x4;

__device__ __forceinline__ unsigned short f2bf_rne(float f) {
  union { float f; unsigned u; } v;
  v.f = f;
  unsigned u = v.u;
  return (unsigned short)((u + 0x7FFFu + ((u >> 16) & 1u)) >> 16);
}

// Prepass: xb[i][k] = bf16(y_i * x[i][k]); blocks 0..63 additionally
// (a) write the packed per-sample column record yw[i] = {y_i, relu(a_i)},
// (b) reduce {relu(alpha), relu(xi), y} into per-block triples.
__global__ __launch_bounds__(256) void prep_kernel(
    const float* __restrict__ x, const float* __restrict__ y,
    const float* __restrict__ alpha, const float* __restrict__ xi,
    unsigned short* __restrict__ xb, float2* __restrict__ yw,
    float4* __restrict__ psums) {
  int t = blockIdx.x * 256 + threadIdx.x;  // 0 .. 262143
  int base = t * 4;
  int row = base >> 6;  // D=64
  float yv = y[row];
  float4 v = *(const float4*)(x + base);
  u16x4 o;
  o.x = f2bf_rne(v.x * yv);
  o.y = f2bf_rne(v.y * yv);
  o.z = f2bf_rne(v.z * yv);
  o.w = f2bf_rne(v.w * yv);
  *(u16x4*)(xb + base) = o;

  if (blockIdx.x < (N_SAMP / 256)) {
    float a = fmaxf(alpha[t], 0.0f);
    float xr = fmaxf(xi[t], 0.0f);
    float yy = y[t];
    yw[t] = make_float2(yy, a);  // packed column record
#pragma unroll
    for (int off = 32; off > 0; off >>= 1) {
      a += __shfl_down(a, off, 64);
      xr += __shfl_down(xr, off, 64);
      yy += __shfl_down(yy, off, 64);
    }
    __shared__ float ra[4], rx[4], ry[4];
    int wv = threadIdx.x >> 6;
    if ((threadIdx.x & 63) == 0) {
      ra[wv] = a;
      rx[wv] = xr;
      ry[wv] = yy;
    }
    __syncthreads();
    if (threadIdx.x == 0)
      psums[blockIdx.x] =
          make_float4(ra[0] + ra[1] + ra[2] + ra[3],
                      rx[0] + rx[1] + rx[2] + rx[3],
                      ry[0] + ry[1] + ry[2] + ry[3], 0.0f);
  }
}

// R10: WAVE-ISOLATION experiment. Kernel body identical to R9 (no-LDS,
// deferred-epilogue, packed yw columns, setprio around MFMA); ONLY the
// schedule changes: SPLIT 8->4 => 256 blocks = 1 block/CU = 1 wave/SIMD,
// gcnt ~= 32. The 3230cy/wave-tile wall has survived depth, TLP-up,
// datapath, instr-count, and stagger changes — the last untested axis is
// the phase-locked pair of co-resident waves per SIMD (identical periodic
// loops started simultaneously: both issue loads together, epilogue
// together, wait together). 1 wave/SIMD removes ALL inter-wave effects.
// Pre-committed read: tile <=32us => interference was the wall (pursue);
// tile 60-90us => per-wave latency is the wall and, with R3's full-window
// prefetch null at 2 waves, 43us is the practical floor (declare plateau).
__global__ __launch_bounds__(256, 2) void tile_kernel(
    const unsigned short* __restrict__ xb,
    const float* __restrict__ alpha,
    const float* __restrict__ y,
    const float2* __restrict__ yw,
    const int* __restrict__ coeffp,
    const int* __restrict__ degp,
    float* __restrict__ partials) {
  __shared__ float wred[4];

  const int tid = threadIdx.x;
  const int lane = tid & 63;
  const int wv = tid >> 6;  // wave 0..3
  const int wm = wv >> 1;   // quadrant row (0..1)
  const int wn = wv & 1;    // quadrant col (0..1)
  const int lr = lane & 15;
  const int q = lane >> 4;  // quad 0..3

  // ---- balanced schedule: pair p = {rows p, 127-p}, segment sb ----
  const int p = blockIdx.x >> 2;           // pair 0..63
  const int sb = blockIdx.x & (SPLIT - 1); // segment 0..3
  const int i1 = p, i2 = NTILE - 1 - p;
  const int cnt1 = NTILE - p;  // tiles in row i1 (j = p..127)
  const int g0 = sb * SEG_BASE + (sb < SEG_REM ? sb : SEG_REM);
  const int gcnt = SEG_BASE + (sb < SEG_REM ? 1 : 0);

  auto g_to_ij = [&](int g, int& i, int& j) {
    if (g < cnt1) {
      i = i1;
      j = p + g;
    } else {
      i = i2;
      j = i2 + (g - cnt1);
    }
  };

  const char* xbytes = (const char*)xb;
  const float fco = (float)coeffp[0];
  const int deg = degp[0];

  f32x2 yr[4][2], ar[4][2];
  auto load_rows = [&](int ic) {
#pragma unroll
    for (int mt = 0; mt < 4; ++mt) {
      int idx = ic * TILE + wm * 64 + mt * 16 + q * 4;
      float4 yv = *(const float4*)(y + idx);
      float4 av = *(const float4*)(alpha + idx);
      yr[mt][0] = (f32x2){yv.x, yv.y};
      yr[mt][1] = (f32x2){yv.z, yv.w};
      ar[mt][0] = (f32x2){fmaxf(av.x, 0.0f), fmaxf(av.y, 0.0f)};
      ar[mt][1] = (f32x2){fmaxf(av.z, 0.0f), fmaxf(av.w, 0.0f)};
    }
  };

  bf16x8 af[4][2];
  auto read_af_g = [&](int rowtile) {
    const char* base = xbytes + (((size_t)(rowtile * TILE + wm * 64)) << 7);
#pragma unroll
    for (int mt = 0; mt < 4; ++mt) {
      int r = mt * 16 + lr;
#pragma unroll
      for (int kc = 0; kc < 2; ++kc)
        af[mt][kc] = *(const bf16x8*)(base + (r << 7) + ((kc * 4 + q) << 4));
    }
  };

  f32x2 rsum[4][2];
#pragma unroll
  for (int mt = 0; mt < 4; ++mt)
    for (int h = 0; h < 2; ++h) rsum[mt][h] = (f32x2){0.0f, 0.0f};
  float lane_total = 0.0f;

  auto flush_rsum = [&]() {
#pragma unroll
    for (int mt = 0; mt < 4; ++mt) {
      f32x2 s = rsum[mt][0] * ar[mt][0] + rsum[mt][1] * ar[mt][1];
      lane_total += s.x + s.y;
      rsum[mt][0] = (f32x2){0.0f, 0.0f};
      rsum[mt][1] = (f32x2){0.0f, 0.0f};
    }
  };

  // ---- deferred-epilogue state (tile n-1) ----
  f32x4 acc[4][4];
  float ycolP[4], wcolP[4];
  bool diagP = false;
  bool have_prev = false;

  auto epilogue_prev = [&]() {
    if (deg == 3) {
      if (diagP) {
#pragma unroll
        for (int nt = 0; nt < 4; ++nt) {
          f32x2 cs = {0.0f, 0.0f};
#pragma unroll
          for (int mt = 0; mt < 4; ++mt) {
#pragma unroll
            for (int h = 0; h < 2; ++h) {
              f32x2 T = {acc[mt][nt][2 * h], acc[mt][nt][2 * h + 1]};
              f32x2 T2 = T * T;
              cs += T2 * T;
            }
          }
          lane_total = fmaf(cs.x + cs.y, wcolP[nt], lane_total);
        }
      } else {
#pragma unroll
        for (int nt = 0; nt < 4; ++nt) {
          f32x2 cs = {0.0f, 0.0f};
#pragma unroll
          for (int mt = 0; mt < 4; ++mt) {
#pragma unroll
            for (int h = 0; h < 2; ++h) {
              f32x2 T = {acc[mt][nt][2 * h], acc[mt][nt][2 * h + 1]};
              f32x2 T2 = T * T;
              f32x2 P = T2 * T;
              cs += P;
              rsum[mt][h] += P;  // a_i applied at flush (fixed per row)
            }
          }
          lane_total = fmaf(cs.x + cs.y, wcolP[nt], lane_total);
        }
      }
    } else {
      // generic-degree fallback (even degree restores y_i y_j sign);
      // runs BEFORE any row-switch load_rows of the current iteration.
#pragma unroll
      for (int nt = 0; nt < 4; ++nt) {
        float cs = 0.0f;
#pragma unroll
        for (int mt = 0; mt < 4; ++mt) {
          float ys[4] = {yr[mt][0].x, yr[mt][0].y, yr[mt][1].x, yr[mt][1].y};
          float as[4] = {ar[mt][0].x, ar[mt][0].y, ar[mt][1].x, ar[mt][1].y};
#pragma unroll
          for (int rg = 0; rg < 4; ++rg) {
            float T = acc[mt][nt][rg];
            float pw = 1.0f;
            for (int d = 0; d < deg; ++d) pw *= T;
            if (!(deg & 1)) pw *= ys[rg] * ycolP[nt];
            cs += pw;
            if (!diagP) lane_total += pw * as[rg];
          }
        }
        lane_total = fmaf(cs, wcolP[nt], lane_total);
      }
    }
  };

  // ---- prologue: first row's A/y/alpha ----
  int icur;
  {
    int j0;
    g_to_ij(g0, icur, j0);
    load_rows(icur);
    read_af_g(icur);
  }

  for (int it = 0; it < gcnt; ++it) {
    int g = g0 + it;
    int i, j;
    g_to_ij(g, i, j);

    // ---- 1. issue this tile's B fragments (direct from global, L2-hot) ----
    const char* bbase = xbytes + (((size_t)(j * TILE + wn * 64)) << 7);
    bf16x8 bfr[4][2];
#pragma unroll
    for (int nt = 0; nt < 4; ++nt) {
      int rr = nt * 16 + lr;
#pragma unroll
      for (int kc = 0; kc < 2; ++kc)
        bfr[nt][kc] = *(const bf16x8*)(bbase + (rr << 7) + ((kc * 4 + q) << 4));
    }

    // ---- 2. issue this tile's packed column records (4 dwordx2) ----
    const float2* cwp = yw + j * TILE + wn * 64 + lr;
    float2 cw0 = cwp[0];
    float2 cw1 = cwp[16];
    float2 cw2 = cwp[32];
    float2 cw3 = cwp[48];

    // ---- 3. previous tile's epilogue runs in the load shadow ----
    if (have_prev) epilogue_prev();

    // ---- 4. row switch (after epilogue: flush uses old row's ar) ----
    if (i != icur) {
      flush_rsum();
      load_rows(i);
      read_af_g(i);  // global, L2-hot; rare (once per block typically)
      icur = i;
    }

    // ---- 5. acc init (y_i * y_j * coeff) + MFMA ----
    float ycolN[4] = {cw0.x, cw1.x, cw2.x, cw3.x};
    float wcolN[4] = {cw0.y, cw1.y, cw2.y, cw3.y};
    float ysc[4];
#pragma unroll
    for (int nt = 0; nt < 4; ++nt) ysc[nt] = ycolN[nt] * fco;

#pragma unroll
    for (int mt = 0; mt < 4; ++mt) {
#pragma unroll
      for (int nt = 0; nt < 4; ++nt) {
        f32x2 lo = yr[mt][0] * ysc[nt];
        f32x2 hi = yr[mt][1] * ysc[nt];
        acc[mt][nt][0] = lo.x;
        acc[mt][nt][1] = lo.y;
        acc[mt][nt][2] = hi.x;
        acc[mt][nt][3] = hi.y;
      }
    }

    __builtin_amdgcn_s_setprio(1);
#pragma unroll
    for (int kc = 0; kc < 2; ++kc) {
#pragma unroll
      for (int mt = 0; mt < 4; ++mt) {
#pragma unroll
        for (int nt = 0; nt < 4; ++nt) {
          acc[mt][nt] = __builtin_amdgcn_mfma_f32_16x16x32_bf16(
              af[mt][kc], bfr[nt][kc], acc[mt][nt], 0, 0, 0);
        }
      }
    }
    __builtin_amdgcn_s_setprio(0);

    // ---- 6. rotate deferred state (wcol already relu'd by prep) ----
#pragma unroll
    for (int nt = 0; nt < 4; ++nt) {
      ycolP[nt] = ycolN[nt];
      wcolP[nt] = wcolN[nt];
    }
    diagP = (j == i);
    have_prev = true;
  }

  // ---- drain: last tile's epilogue + last row's flush ----
  epilogue_prev();
  flush_rsum();

  // ---- the only block sync: final 4-wave reduce ----
#pragma unroll
  for (int off = 32; off > 0; off >>= 1)
    lane_total += __shfl_down(lane_total, off, 64);
  if (lane == 0) wred[wv] = lane_total;
  __syncthreads();
  if (tid == 0)
    partials[blockIdx.x] = wred[0] + wred[1] + wred[2] + wred[3];
}

__global__ __launch_bounds__(256) void finalize_kernel(
    const float* __restrict__ partials,
    const float4* __restrict__ psums,
    const float* __restrict__ bp,
    const int* __restrict__ Cp,
    const int* __restrict__ lamp,
    float* __restrict__ out) {
  double tsum = 0.0, sa = 0.0, sx = 0.0, sy = 0.0;
  for (int i = threadIdx.x; i < NBLOCKS; i += 256) tsum += (double)partials[i];
  if (threadIdx.x < (N_SAMP / 256)) {  // 64 triples, wave 0 only
    float4 v = psums[threadIdx.x];
    sa = (double)v.x;
    sx = (double)v.y;
    sy = (double)v.z;
  }
#pragma unroll
  for (int off = 32; off > 0; off >>= 1) {
    tsum += __shfl_down(tsum, off, 64);
    sa += __shfl_down(sa, off, 64);
    sx += __shfl_down(sx, off, 64);
    sy += __shfl_down(sy, off, 64);
  }
  __shared__ double red[4][4];
  int wv = threadIdx.x >> 6;
  if ((threadIdx.x & 63) == 0) {
    red[wv][0] = tsum;
    red[wv][1] = sa;
    red[wv][2] = sx;
    red[wv][3] = sy;
  }
  __syncthreads();
  if (threadIdx.x == 0) {
    double T = red[0][0] + red[1][0] + red[2][0] + red[3][0];
    double A = red[0][1] + red[1][1] + red[2][1] + red[3][1];
    double X = red[0][2] + red[1][2] + red[2][2] + red[3][2];
    double Y = red[0][3] + red[1][3] + red[2][3] + red[3][3];
    double b = (double)bp[0];
    double Cc = (double)Cp[0];
    double lam = (double)lamp[0];
    double mean = (T + b * Y - (double)N_SAMP + X) / (double)N_SAMP;
    out[0] = (float)(0.5 * A + Cc * X + lam * mean);
  }
}

extern "C" void kernel_launch(void* const* d_in, const int* in_sizes, int n_in,
                              void* d_out, int out_size, void* d_ws,
                              size_t ws_size, hipStream_t stream) {
  const float* x = (const float*)d_in[0];
  const float* y = (const float*)d_in[1];
  const float* alpha = (const float*)d_in[2];
  const float* xi = (const float*)d_in[3];
  const float* b = (const float*)d_in[4];
  const int* coeff = (const int*)d_in[5];
  const int* degree = (const int*)d_in[6];
  const int* C = (const int*)d_in[7];
  const int* lambd = (const int*)d_in[8];

  unsigned short* xb = (unsigned short*)d_ws;                  // 2 MB
  char* base2 = (char*)d_ws + (size_t)N_SAMP * D_FEAT * 2;     // +2 MB
  float2* yw = (float2*)base2;                                 // 128 KB
  char* pbase = base2 + (size_t)N_SAMP * sizeof(float2);
  float* partials = (float*)pbase;  // 256 floats
  float4* psums = (float4*)(pbase + ((NBLOCKS * 4 + 255) & ~255));  // 64 f4

  prep_kernel<<<(N_SAMP * D_FEAT) / (4 * 256), 256, 0, stream>>>(
      x, y, alpha, xi, xb, yw, psums);

  tile_kernel<<<NBLOCKS, 256, 0, stream>>>(xb, alpha, y, yw, coeff, degree,
                                           partials);

  finalize_kernel<<<1, 256, 0, stream>>>(partials, psums, b, C, lambd,
                                         (float*)d_out);
}

// Round 11
// 105.035 us; speedup vs baseline: 1.4580x; 1.0777x over previous
//
#include <hip/hip_runtime.h>

#define N_SAMP 16384
#define D_FEAT 64
#define TILE 128
#define NTILE 128                 // 128 tile-rows
#define SPLIT 8                   // wave-segments per row-pair
#define NPAIR (NTILE / 2)         // 64
#define NBLOCKS (NPAIR * SPLIT)   // 512 blocks = exactly 2/CU
#define TPP (NTILE + 1)           // 129 tiles per pair (constant)
#define SEG_BASE (TPP / SPLIT)    // 16
#define SEG_REM (TPP % SPLIT)     // 1

typedef __attribute__((ext_vector_type(8))) short bf16x8;
typedef __attribute__((ext_vector_type(4))) float f32x4;
typedef __attribute__((ext_vector_type(2))) float f32x2;
typedef __attribute__((ext_vector_type(4))) unsigned short u16x4;

typedef __attribute__((address_space(3))) unsigned lds_u32_t;
typedef const __attribute__((address_space(1))) unsigned glb_u32_t;

__device__ __forceinline__ void load16_to_lds(const void* g, void* l) {
  __builtin_amdgcn_global_load_lds((glb_u32_t*)g, (lds_u32_t*)l, 16, 0, 0);
}

__device__ __forceinline__ unsigned short f2bf_rne(float f) {
  union { float f; unsigned u; } v;
  v.f = f;
  unsigned u = v.u;
  return (unsigned short)((u + 0x7FFFu + ((u >> 16) & 1u)) >> 16);
}

// Prepass: xb[i][k] = bf16(y_i * x[i][k]); blocks 0..63 also reduce
// {relu(alpha), relu(xi), y} into per-block triples via plain stores.
__global__ __launch_bounds__(256) void prep_kernel(
    const float* __restrict__ x, const float* __restrict__ y,
    const float* __restrict__ alpha, const float* __restrict__ xi,
    unsigned short* __restrict__ xb, float4* __restrict__ psums) {
  int t = blockIdx.x * 256 + threadIdx.x;  // 0 .. 262143
  int base = t * 4;
  int row = base >> 6;  // D=64
  float yv = y[row];
  float4 v = *(const float4*)(x + base);
  u16x4 o;
  o.x = f2bf_rne(v.x * yv);
  o.y = f2bf_rne(v.y * yv);
  o.z = f2bf_rne(v.z * yv);
  o.w = f2bf_rne(v.w * yv);
  *(u16x4*)(xb + base) = o;

  if (blockIdx.x < (N_SAMP / 256)) {
    float a = fmaxf(alpha[t], 0.0f);
    float xr = fmaxf(xi[t], 0.0f);
    float yy = y[t];
#pragma unroll
    for (int off = 32; off > 0; off >>= 1) {
      a += __shfl_down(a, off, 64);
      xr += __shfl_down(xr, off, 64);
      yy += __shfl_down(yy, off, 64);
    }
    __shared__ float ra[4], rx[4], ry[4];
    int wv = threadIdx.x >> 6;
    if ((threadIdx.x & 63) == 0) {
      ra[wv] = a;
      rx[wv] = xr;
      ry[wv] = yy;
    }
    __syncthreads();
    if (threadIdx.x == 0)
      psums[blockIdx.x] =
          make_float4(ra[0] + ra[1] + ra[2] + ra[3],
                      rx[0] + rx[1] + rx[2] + rx[3],
                      ry[0] + ry[1] + ry[2] + ry[3], 0.0f);
  }
}

// BEST-KNOWN configuration (session R3, 107.03us measured):
// barrier-free K-loop, per-wave private 2x8KB double-buffered B chunk via
// global_load_lds + vmcnt(8) counted wait, global-side XOR swizzle for
// conflict-free ds_read_b128, column y/alpha software-pipelined one tile
// ahead, rsum a_i deferral, co-resident block phase stagger.
// Ten rounds of structural probes (grid-sync fusion, atomic-tail fusion,
// column pipeline, stagger, 8-wave TLP, 3-4 blocks/CU TLP, no-LDS direct-L2,
// depth-2 reg dbuf, VMEM instr cut, 1-wave isolation) all landed neutral,
// spill-invalidated, or worse: the tile floor is 43-45us in an issue-/
// clock-limited regime not addressable at HIP source level.
__global__ __launch_bounds__(256, 2) void tile_kernel(
    const unsigned short* __restrict__ xb,
    const float* __restrict__ alpha,
    const float* __restrict__ y,
    const int* __restrict__ coeffp,
    const int* __restrict__ degp,
    float* __restrict__ partials) {
  __shared__ unsigned short smB[4][2][64 * 64];  // 4 waves x 2 bufs x 8 KB
  __shared__ float wred[4];

  const int tid = threadIdx.x;
  const int lane = tid & 63;
  const int wv = tid >> 6;  // wave 0..3
  const int wm = wv >> 1;   // quadrant row (0..1)
  const int wn = wv & 1;    // quadrant col (0..1)
  const int lr = lane & 15;
  const int q = lane >> 4;  // quad 0..3

  // ---- balanced schedule: pair p = {rows p, 127-p}, segment sb ----
  const int p = blockIdx.x >> 3;
  const int sb = blockIdx.x & (SPLIT - 1);
  const int i1 = p, i2 = NTILE - 1 - p;
  const int cnt1 = NTILE - p;  // tiles in row i1 (j = p..127)
  const int g0 = sb * SEG_BASE + (sb < SEG_REM ? sb : SEG_REM);
  const int gcnt = SEG_BASE + (sb < SEG_REM ? 1 : 0);

  // phase stagger: co-resident block pair differs in bit 8
  const int ph = ((blockIdx.x >> 8) & 1) * (gcnt >> 1);
  auto map_g = [&](int it) {
    int gg = it + ph;
    if (gg >= gcnt) gg -= gcnt;
    return g0 + gg;
  };
  auto g_to_ij = [&](int g, int& i, int& j) {
    if (g < cnt1) {
      i = i1;
      j = p + g;
    } else {
      i = i2;
      j = i2 + (g - cnt1);
    }
  };

  const char* xbytes = (const char*)xb;
  char* mybuf = (char*)smB + (wv << 14);  // 16 KB per wave

  const float fco = (float)coeffp[0];
  const int deg = degp[0];

  // global-side swizzle: lane carries chunk (r = L*8 + lane/8,
  // c = (lane&7) ^ (r&7)); HW scatters to base+lane*16 -> LDS slot r*8+c^..
  const int swz =
      ((lane >> 3) << 7) + (((lane & 7) ^ ((lane >> 3) & 7)) << 4);

  auto stage_wave = [&](int coltile, int k) {
    const char* gbase =
        xbytes + (((size_t)(coltile * TILE + wn * 64)) << 7) + swz;
    char* dst = mybuf + (k << 13);
#pragma unroll
    for (int L = 0; L < 8; ++L)
      load16_to_lds(gbase + (L << 10), dst + (L << 10));
  };

  f32x2 yr[4][2], ar[4][2];
  auto load_rows = [&](int ic) {
#pragma unroll
    for (int mt = 0; mt < 4; ++mt) {
      int idx = ic * TILE + wm * 64 + mt * 16 + q * 4;
      float4 yv = *(const float4*)(y + idx);
      float4 av = *(const float4*)(alpha + idx);
      yr[mt][0] = (f32x2){yv.x, yv.y};
      yr[mt][1] = (f32x2){yv.z, yv.w};
      ar[mt][0] = (f32x2){fmaxf(av.x, 0.0f), fmaxf(av.y, 0.0f)};
      ar[mt][1] = (f32x2){fmaxf(av.z, 0.0f), fmaxf(av.w, 0.0f)};
    }
  };

  bf16x8 af[4][2];
  auto read_af_g = [&](int rowtile) {
    const char* base = xbytes + (((size_t)(rowtile * TILE + wm * 64)) << 7);
#pragma unroll
    for (int mt = 0; mt < 4; ++mt) {
      int r = mt * 16 + lr;
#pragma unroll
      for (int kc = 0; kc < 2; ++kc)
        af[mt][kc] = *(const bf16x8*)(base + (r << 7) + ((kc * 4 + q) << 4));
    }
  };

  f32x2 rsum[4][2];
#pragma unroll
  for (int mt = 0; mt < 4; ++mt)
    for (int h = 0; h < 2; ++h) rsum[mt][h] = (f32x2){0.0f, 0.0f};
  float lane_total = 0.0f;

  auto flush_rsum = [&]() {
#pragma unroll
    for (int mt = 0; mt < 4; ++mt) {
      f32x2 s = rsum[mt][0] * ar[mt][0] + rsum[mt][1] * ar[mt][1];
      lane_total += s.x + s.y;
      rsum[mt][0] = (f32x2){0.0f, 0.0f};
      rsum[mt][1] = (f32x2){0.0f, 0.0f};
    }
  };

  // ---- prologue: first B chunk into buf 0; first tile's columns; rows ----
  int gfirst = map_g(0);
  int icur, jfirst;
  g_to_ij(gfirst, icur, jfirst);
  stage_wave(jfirst, 0);

  float ycol[4], wcol[4];
#pragma unroll
  for (int nt = 0; nt < 4; ++nt) {
    int jj = jfirst * TILE + wn * 64 + nt * 16 + lr;
    ycol[nt] = y[jj];
    wcol[nt] = fmaxf(alpha[jj], 0.0f);
  }
  load_rows(icur);
  read_af_g(icur);

  for (int it = 0; it < gcnt; ++it) {
    int g = map_g(it);
    int i, j;
    g_to_ij(g, i, j);
    char* bufc = mybuf + ((it & 1) << 13);

    if (i != icur) {
      flush_rsum();     // old row's a_i weights
      load_rows(i);
      read_af_g(i);     // global, L2-hot; at most twice per block
      icur = i;
    }

    // ---- prefetch next B chunk, then wait so only it stays in flight ----
    int jnext = 0;
    bool have_next = (it + 1 < gcnt);
    if (have_next) {
      int gn = map_g(it + 1);
      int in_, jn;
      g_to_ij(gn, in_, jn);
      jnext = jn;
      stage_wave(jn, (it + 1) & 1);
      // drain everything older than the 8 prefetch loads (incl. bufc stage
      // and last iteration's column loads, both issued a full tile ago)
      __builtin_amdgcn_s_waitcnt(0x0F78);  // vmcnt(8)
    } else {
      __builtin_amdgcn_s_waitcnt(0x0F70);  // vmcnt(0): last tile, full drain
    }

    // ---- issue NEXT tile's column y/alpha now; latency hides under
    // acc-init + MFMA + epilogue (~700cy). fmaxf deferred to rotate. ----
    float ycol_n[4], wraw_n[4];
    if (have_next) {
#pragma unroll
      for (int nt = 0; nt < 4; ++nt) {
        int jj = jnext * TILE + wn * 64 + nt * 16 + lr;
        ycol_n[nt] = y[jj];
        wraw_n[nt] = alpha[jj];
      }
    }

    // ---- acc init: y_i * y_j * coeff (ycol already in regs) ----
    float ysc[4];
#pragma unroll
    for (int nt = 0; nt < 4; ++nt) ysc[nt] = ycol[nt] * fco;

    f32x4 acc[4][4];
#pragma unroll
    for (int mt = 0; mt < 4; ++mt) {
#pragma unroll
      for (int nt = 0; nt < 4; ++nt) {
        f32x2 lo = yr[mt][0] * ysc[nt];
        f32x2 hi = yr[mt][1] * ysc[nt];
        acc[mt][nt][0] = lo.x;
        acc[mt][nt][1] = lo.y;
        acc[mt][nt][2] = hi.x;
        acc[mt][nt][3] = hi.y;
      }
    }

    // ---- MFMA: per-kc B frags from the wave-private chunk ----
#pragma unroll
    for (int kc = 0; kc < 2; ++kc) {
      bf16x8 bfr[4];
#pragma unroll
      for (int nt = 0; nt < 4; ++nt) {
        int rr = nt * 16 + lr;  // row within the 64-row chunk
        bfr[nt] = *(const bf16x8*)(bufc + (rr << 7) +
                                   (((kc * 4 + q) ^ (rr & 7)) << 4));
      }
#pragma unroll
      for (int mt = 0; mt < 4; ++mt) {
#pragma unroll
        for (int nt = 0; nt < 4; ++nt) {
          acc[mt][nt] = __builtin_amdgcn_mfma_f32_16x16x32_bf16(
              af[mt][kc], bfr[nt], acc[mt][nt], 0, 0, 0);
        }
      }
    }

    // ---- epilogue ----
    bool diagonal = (j == i);
    if (deg == 3) {
      if (diagonal) {
#pragma unroll
        for (int nt = 0; nt < 4; ++nt) {
          f32x2 cs = {0.0f, 0.0f};
#pragma unroll
          for (int mt = 0; mt < 4; ++mt) {
#pragma unroll
            for (int h = 0; h < 2; ++h) {
              f32x2 T = {acc[mt][nt][2 * h], acc[mt][nt][2 * h + 1]};
              f32x2 T2 = T * T;
              cs += T2 * T;
            }
          }
          lane_total = fmaf(cs.x + cs.y, wcol[nt], lane_total);
        }
      } else {
#pragma unroll
        for (int nt = 0; nt < 4; ++nt) {
          f32x2 cs = {0.0f, 0.0f};
#pragma unroll
          for (int mt = 0; mt < 4; ++mt) {
#pragma unroll
            for (int h = 0; h < 2; ++h) {
              f32x2 T = {acc[mt][nt][2 * h], acc[mt][nt][2 * h + 1]};
              f32x2 T2 = T * T;
              f32x2 P = T2 * T;
              cs += P;
              rsum[mt][h] += P;  // a_i applied at flush (fixed per row)
            }
          }
          lane_total = fmaf(cs.x + cs.y, wcol[nt], lane_total);
        }
      }
    } else {
      // generic-degree fallback (even degree restores y_i y_j sign)
#pragma unroll
      for (int nt = 0; nt < 4; ++nt) {
        float cs = 0.0f;
#pragma unroll
        for (int mt = 0; mt < 4; ++mt) {
          float ys[4] = {yr[mt][0].x, yr[mt][0].y, yr[mt][1].x, yr[mt][1].y};
          float as[4] = {ar[mt][0].x, ar[mt][0].y, ar[mt][1].x, ar[mt][1].y};
#pragma unroll
          for (int rg = 0; rg < 4; ++rg) {
            float T = acc[mt][nt][rg];
            float pw = 1.0f;
            for (int d = 0; d < deg; ++d) pw *= T;
            if (!(deg & 1)) pw *= ys[rg] * ycol[nt];
            cs += pw;
            if (!diagonal) lane_total += pw * as[rg];
          }
        }
        lane_total = fmaf(cs, wcol[nt], lane_total);
      }
    }

    // ---- rotate pipelined columns (load completed ~700cy ago) ----
    if (have_next) {
#pragma unroll
      for (int nt = 0; nt < 4; ++nt) {
        ycol[nt] = ycol_n[nt];
        wcol[nt] = fmaxf(wraw_n[nt], 0.0f);
      }
    }
    // no barrier: buffer reuse is safe per-wave (ds_reads of buf n were
    // consumed two iterations ago, in order, within this wave)
  }

  flush_rsum();  // last row's a_i weights

  // ---- the only block sync: final 4-wave reduce ----
#pragma unroll
  for (int off = 32; off > 0; off >>= 1)
    lane_total += __shfl_down(lane_total, off, 64);
  if (lane == 0) wred[wv] = lane_total;
  __syncthreads();
  if (tid == 0)
    partials[blockIdx.x] = wred[0] + wred[1] + wred[2] + wred[3];
}

__global__ __launch_bounds__(256) void finalize_kernel(
    const float* __restrict__ partials,
    const float4* __restrict__ psums,
    const float* __restrict__ bp,
    const int* __restrict__ Cp,
    const int* __restrict__ lamp,
    float* __restrict__ out) {
  double tsum = 0.0, sa = 0.0, sx = 0.0, sy = 0.0;
  for (int i = threadIdx.x; i < NBLOCKS; i += 256) tsum += (double)partials[i];
  if (threadIdx.x < (N_SAMP / 256)) {  // 64 triples, wave 0 only
    float4 v = psums[threadIdx.x];
    sa = (double)v.x;
    sx = (double)v.y;
    sy = (double)v.z;
  }
#pragma unroll
  for (int off = 32; off > 0; off >>= 1) {
    tsum += __shfl_down(tsum, off, 64);
    sa += __shfl_down(sa, off, 64);
    sx += __shfl_down(sx, off, 64);
    sy += __shfl_down(sy, off, 64);
  }
  __shared__ double red[4][4];
  int wv = threadIdx.x >> 6;
  if ((threadIdx.x & 63) == 0) {
    red[wv][0] = tsum;
    red[wv][1] = sa;
    red[wv][2] = sx;
    red[wv][3] = sy;
  }
  __syncthreads();
  if (threadIdx.x == 0) {
    double T = red[0][0] + red[1][0] + red[2][0] + red[3][0];
    double A = red[0][1] + red[1][1] + red[2][1] + red[3][1];
    double X = red[0][2] + red[1][2] + red[2][2] + red[3][2];
    double Y = red[0][3] + red[1][3] + red[2][3] + red[3][3];
    double b = (double)bp[0];
    double Cc = (double)Cp[0];
    double lam = (double)lamp[0];
    double mean = (T + b * Y - (double)N_SAMP + X) / (double)N_SAMP;
    out[0] = (float)(0.5 * A + Cc * X + lam * mean);
  }
}

extern "C" void kernel_launch(void* const* d_in, const int* in_sizes, int n_in,
                              void* d_out, int out_size, void* d_ws,
                              size_t ws_size, hipStream_t stream) {
  const float* x = (const float*)d_in[0];
  const float* y = (const float*)d_in[1];
  const float* alpha = (const float*)d_in[2];
  const float* xi = (const float*)d_in[3];
  const float* b = (const float*)d_in[4];
  const int* coeff = (const int*)d_in[5];
  const int* degree = (const int*)d_in[6];
  const int* C = (const int*)d_in[7];
  const int* lambd = (const int*)d_in[8];

  unsigned short* xb = (unsigned short*)d_ws;  // 2 MB
  char* pbase = (char*)d_ws + (size_t)N_SAMP * D_FEAT * 2;
  float* partials = (float*)pbase;  // 512 floats
  float4* psums = (float4*)(pbase + ((NBLOCKS * 4 + 255) & ~255));  // 64 f4

  prep_kernel<<<(N_SAMP * D_FEAT) / (4 * 256), 256, 0, stream>>>(x, y, alpha,
                                                                 xi, xb, psums);

  tile_kernel<<<NBLOCKS, 256, 0, stream>>>(xb, alpha, y, coeff, degree,
                                           partials);

  finalize_kernel<<<1, 256, 0, stream>>>(partials, psums, b, C, lambd,
                                         (float*)d_out);
}